// Round 5
// baseline (205.615 us; speedup 1.0000x reference)
//
#include <hip/hip_runtime.h>

#define N_VOX 100000
#define K3 125
#define CENTER_K 62
#define CAP 4096
#define EPSF 1e-5f

// ws layout (float-word offsets)
#define CNT 0                              // 125 counters padded x16 (2048 words)
#define PRS 2048                           // int2 pairs [125][CAP] = 1,024,000 words
#define ACC (2048 + 2 * 125 * CAP)         // accA [N][32]  (zeroed via memset)
#define ACV (ACC + N_VOX * 32)             // accV [N][16]  (zeroed via memset)
#define CAT (ACV + N_VOX * 16)             // cat  [N][32]
// end = 9,026,048 words = 36.1 MB

// one pass over nbr -> per-k pair lists (center tap handled densely in finalize)
__global__ __launch_bounds__(256) void build_pairs(const int* __restrict__ nbr,
                                                   float* __restrict__ ws)
{
    int* cnt = (int*)(ws + CNT);
    int2* pairs = (int2*)(ws + PRS);
    const int TOT4 = (N_VOX * K3) / 4;   // 3,125,000 exact
    const int4* n4 = (const int4*)nbr;
    for (int i4 = blockIdx.x * 256 + threadIdx.x; i4 < TOT4; i4 += gridDim.x * 256) {
        int4 v = n4[i4];
        int base = i4 * 4;
        int idxs[4] = {v.x, v.y, v.z, v.w};
        #pragma unroll
        for (int j = 0; j < 4; ++j) {
            int idx = idxs[j];
            int i = base + j;
            int n = i / K3;              // magic-mul
            int k = i - n * K3;
            if (idx < N_VOX && k != CENTER_K) {
                int pos = atomicAdd(&cnt[k * 16], 1);
                if (pos < CAP) pairs[(size_t)k * CAP + pos] = make_int2(n, idx);
            }
        }
    }
}

// ---- scatterA: img+pts conv, 32 lanes per pair, 2-deep pipelined ----
__device__ __forceinline__ void loadFA(float4 (&F)[12], int2 pr,
    const float4* __restrict__ fi4, const float4* __restrict__ fp4, int h)
{
    const float4* fi = fi4 + (size_t)pr.y * 16 + h * 8;
    const float4* fp = fp4 + (size_t)pr.y * 8 + h * 4;
    #pragma unroll
    for (int j = 0; j < 8; ++j) F[j] = fi[j];
    #pragma unroll
    for (int j = 0; j < 4; ++j) F[8 + j] = fp[j];
}

__device__ __forceinline__ void computeFA(const float4 (&F)[12],
    const float (&Wi)[32], const float (&Wp)[16], float& aI, float& aP)
{
    float a0 = 0.f, a1 = 0.f, b0 = 0.f, b1 = 0.f;
    #pragma unroll
    for (int j = 0; j < 4; ++j) {
        float4 f = F[j];
        a0 += f.x*Wi[4*j] + f.y*Wi[4*j+1] + f.z*Wi[4*j+2] + f.w*Wi[4*j+3];
        float4 g = F[4 + j];
        a1 += g.x*Wi[16+4*j] + g.y*Wi[16+4*j+1] + g.z*Wi[16+4*j+2] + g.w*Wi[16+4*j+3];
    }
    #pragma unroll
    for (int j = 0; j < 2; ++j) {
        float4 f = F[8 + j];
        b0 += f.x*Wp[4*j] + f.y*Wp[4*j+1] + f.z*Wp[4*j+2] + f.w*Wp[4*j+3];
        float4 g = F[10 + j];
        b1 += g.x*Wp[8+4*j] + g.y*Wp[8+4*j+1] + g.z*Wp[8+4*j+2] + g.w*Wp[8+4*j+3];
    }
    aI = a0 + a1; aP = b0 + b1;
}

__global__ __launch_bounds__(256) void scatterA(
    const float* __restrict__ fimg, const float* __restrict__ fpts,
    const float* __restrict__ Wimg, const float* __restrict__ Wpts,
    float* __restrict__ ws)
{
    const int k = blockIdx.x;
    const int lane = threadIdx.x & 63;
    const int wv = threadIdx.x >> 6;
    const int s = lane >> 5;            // pair slot within wave (2 pairs/wave)
    const int h = (lane >> 4) & 1;      // c-half
    const int o = lane & 15;

    float Wi[32];
    #pragma unroll
    for (int j = 0; j < 32; ++j) Wi[j] = Wimg[k * 1024 + (h * 32 + j) * 16 + o];
    float Wp[16];
    #pragma unroll
    for (int j = 0; j < 16; ++j) Wp[j] = Wpts[k * 512 + (h * 16 + j) * 16 + o];

    int cnt = ((const int*)(ws + CNT))[k * 16];
    if (cnt > CAP) cnt = CAP;
    const int2* __restrict__ pairs = (const int2*)(ws + PRS) + (size_t)k * CAP;
    float* __restrict__ acc = ws + ACC;
    const float4* __restrict__ fi4 = (const float4*)fimg;
    const float4* __restrict__ fp4 = (const float4*)fpts;

    const int S = gridDim.y * 8;                   // total pair-streams
    int p = (blockIdx.y * 4 + wv) * 2 + s;

    int2 prA = make_int2(0, 0), prB = make_int2(0, 0);
    if (p < cnt) prA = pairs[p];
    if (p + S < cnt) prB = pairs[p + S];
    float4 FA[12], FB[12];
    loadFA(FA, prA, fi4, fp4, h);

    while (p < cnt) {
        {   // body 1: compute prA from FA; fill FB for prB; prefetch prC
            int2 prC = make_int2(0, 0);
            if (p + 2 * S < cnt) prC = pairs[p + 2 * S];
            loadFA(FB, prB, fi4, fp4, h);
            float aI, aP;
            computeFA(FA, Wi, Wp, aI, aP);
            aI += __shfl_xor(aI, 16); aP += __shfl_xor(aP, 16);
            atomicAdd(&acc[(size_t)prA.x * 32 + h * 16 + o], h ? aP : aI);
            p += S; prA = prB; prB = prC;
        }
        if (p >= cnt) break;
        {   // body 2: compute prA from FB; fill FA for prB; prefetch prC
            int2 prC = make_int2(0, 0);
            if (p + 2 * S < cnt) prC = pairs[p + 2 * S];
            loadFA(FA, prB, fi4, fp4, h);
            float aI, aP;
            computeFA(FB, Wi, Wp, aI, aP);
            aI += __shfl_xor(aI, 16); aP += __shfl_xor(aP, 16);
            atomicAdd(&acc[(size_t)prA.x * 32 + h * 16 + o], h ? aP : aI);
            p += S; prA = prB; prB = prC;
        }
    }
}

// ---- scatterV: vis conv on cat, 16 lanes per pair, 2-deep pipelined ----
__device__ __forceinline__ void loadFV(float4 (&F)[8], int2 pr,
    const float4* __restrict__ c4)
{
    const float4* cr = c4 + (size_t)pr.y * 8;
    #pragma unroll
    for (int j = 0; j < 8; ++j) F[j] = cr[j];
}

__device__ __forceinline__ void computeFV(const float4 (&F)[8],
    const float (&Wv)[32], float& aV)
{
    float a0 = 0.f, a1 = 0.f;
    #pragma unroll
    for (int j = 0; j < 4; ++j) {
        float4 f = F[j];
        a0 += f.x*Wv[4*j] + f.y*Wv[4*j+1] + f.z*Wv[4*j+2] + f.w*Wv[4*j+3];
        float4 g = F[4 + j];
        a1 += g.x*Wv[16+4*j] + g.y*Wv[16+4*j+1] + g.z*Wv[16+4*j+2] + g.w*Wv[16+4*j+3];
    }
    aV = a0 + a1;
}

__global__ __launch_bounds__(256) void scatterV(
    const float* __restrict__ Wvis, float* __restrict__ ws)
{
    const int k = blockIdx.x;
    const int lane = threadIdx.x & 63;
    const int wv = threadIdx.x >> 6;
    const int s = lane >> 4;            // 4 pairs/wave
    const int o = lane & 15;

    float Wv[32];
    #pragma unroll
    for (int j = 0; j < 32; ++j) Wv[j] = Wvis[k * 512 + j * 16 + o];

    int cnt = ((const int*)(ws + CNT))[k * 16];
    if (cnt > CAP) cnt = CAP;
    const int2* __restrict__ pairs = (const int2*)(ws + PRS) + (size_t)k * CAP;
    const float4* __restrict__ c4 = (const float4*)(ws + CAT);
    float* __restrict__ accV = ws + ACV;

    const int S = gridDim.y * 16;
    int p = (blockIdx.y * 4 + wv) * 4 + s;

    int2 prA = make_int2(0, 0), prB = make_int2(0, 0);
    if (p < cnt) prA = pairs[p];
    if (p + S < cnt) prB = pairs[p + S];
    float4 FA[8], FB[8];
    loadFV(FA, prA, c4);

    while (p < cnt) {
        {
            int2 prC = make_int2(0, 0);
            if (p + 2 * S < cnt) prC = pairs[p + 2 * S];
            loadFV(FB, prB, c4);
            float aV; computeFV(FA, Wv, aV);
            atomicAdd(&accV[(size_t)prA.x * 16 + o], aV);
            p += S; prA = prB; prB = prC;
        }
        if (p >= cnt) break;
        {
            int2 prC = make_int2(0, 0);
            if (p + 2 * S < cnt) prC = pairs[p + 2 * S];
            loadFV(FA, prB, c4);
            float aV; computeFV(FB, Wv, aV);
            atomicAdd(&accV[(size_t)prA.x * 16 + o], aV);
            p += S; prA = prB; prB = prC;
        }
    }
}

// center tap + BN + ReLU -> cat; thread-per-(voxel,o), center W in VGPRs
__global__ __launch_bounds__(256) void finalizeA(
    const float* __restrict__ fimg, const float* __restrict__ fpts,
    const float* __restrict__ Wimg, const float* __restrict__ Wpts,
    float* __restrict__ ws,
    const float* __restrict__ gi, const float* __restrict__ bi,
    const float* __restrict__ mi, const float* __restrict__ vi,
    const float* __restrict__ gp, const float* __restrict__ bp,
    const float* __restrict__ mp, const float* __restrict__ vp)
{
    int o = threadIdx.x & 15;
    int slot = threadIdx.x >> 4;
    float Wi_r[64];
    #pragma unroll
    for (int c = 0; c < 64; ++c) Wi_r[c] = Wimg[CENTER_K * 1024 + c * 16 + o];
    float Wp_r[32];
    #pragma unroll
    for (int c = 0; c < 32; ++c) Wp_r[c] = Wpts[CENTER_K * 512 + c * 16 + o];
    float sI = gi[o] * rsqrtf(vi[o] + EPSF), bI = bi[o], mI = mi[o];
    float sP = gp[o] * rsqrtf(vp[o] + EPSF), bP = bp[o], mP = mp[o];

    const float4* __restrict__ fi4 = (const float4*)fimg;
    const float4* __restrict__ fp4 = (const float4*)fpts;
    const float* __restrict__ acc = ws + ACC;
    float* __restrict__ cat = ws + CAT;

    for (int n = blockIdx.x * 16 + slot; n < N_VOX; n += gridDim.x * 16) {
        const float4* fr = fi4 + (size_t)n * 16;
        const float4* gr = fp4 + (size_t)n * 8;
        float aI0 = 0.f, aI1 = 0.f, aP0 = 0.f, aP1 = 0.f;
        #pragma unroll
        for (int t = 0; t < 8; ++t) {
            float4 f = fr[t];
            aI0 += f.x*Wi_r[4*t] + f.y*Wi_r[4*t+1] + f.z*Wi_r[4*t+2] + f.w*Wi_r[4*t+3];
            float4 g = fr[8 + t];
            aI1 += g.x*Wi_r[32+4*t] + g.y*Wi_r[32+4*t+1] + g.z*Wi_r[32+4*t+2] + g.w*Wi_r[32+4*t+3];
        }
        #pragma unroll
        for (int t = 0; t < 4; ++t) {
            float4 f = gr[t];
            aP0 += f.x*Wp_r[4*t] + f.y*Wp_r[4*t+1] + f.z*Wp_r[4*t+2] + f.w*Wp_r[4*t+3];
            float4 g = gr[4 + t];
            aP1 += g.x*Wp_r[16+4*t] + g.y*Wp_r[16+4*t+1] + g.z*Wp_r[16+4*t+2] + g.w*Wp_r[16+4*t+3];
        }
        float tI = acc[(size_t)n * 32 + o] + aI0 + aI1;
        float tP = acc[(size_t)n * 32 + 16 + o] + aP0 + aP1;
        cat[(size_t)n * 32 + o]      = fmaxf((tI - mI) * sI + bI, 0.f);
        cat[(size_t)n * 32 + 16 + o] = fmaxf((tP - mP) * sP + bP, 0.f);
    }
}

// vis center + BN + ReLU + sigmoid gate + blend -> out
__global__ __launch_bounds__(256) void finalizeB(
    const float* __restrict__ Wvis, float* __restrict__ ws,
    const float* __restrict__ gv, const float* __restrict__ bv,
    const float* __restrict__ mv, const float* __restrict__ vv,
    const float* __restrict__ w2, float* __restrict__ out)
{
    int o = threadIdx.x & 15;
    int slot = threadIdx.x >> 4;
    float Wv_r[32];
    #pragma unroll
    for (int c = 0; c < 32; ++c) Wv_r[c] = Wvis[CENTER_K * 512 + c * 16 + o];
    float sV = gv[o] * rsqrtf(vv[o] + EPSF), bV = bv[o], mV = mv[o], w2_ = w2[o];

    const float4* __restrict__ c4 = (const float4*)(ws + CAT);
    const float* __restrict__ cat = ws + CAT;
    const float* __restrict__ accV = ws + ACV;

    for (int n = blockIdx.x * 16 + slot; n < N_VOX; n += gridDim.x * 16) {
        const float4* cr = c4 + (size_t)n * 8;
        float a0 = 0.f, a1 = 0.f;
        #pragma unroll
        for (int t = 0; t < 4; ++t) {
            float4 f = cr[t];
            a0 += f.x*Wv_r[4*t] + f.y*Wv_r[4*t+1] + f.z*Wv_r[4*t+2] + f.w*Wv_r[4*t+3];
            float4 g = cr[4 + t];
            a1 += g.x*Wv_r[16+4*t] + g.y*Wv_r[16+4*t+1] + g.z*Wv_r[16+4*t+2] + g.w*Wv_r[16+4*t+3];
        }
        float tV = accV[(size_t)n * 16 + o] + a0 + a1;
        float h = fmaxf((tV - mV) * sV + bV, 0.f);
        float ph = h * w2_;
        ph += __shfl_xor(ph, 1); ph += __shfl_xor(ph, 2);
        ph += __shfl_xor(ph, 4); ph += __shfl_xor(ph, 8);
        float vis = 1.f / (1.f + expf(-ph));
        float xi = cat[(size_t)n * 32 + o];
        float xp = cat[(size_t)n * 32 + 16 + o];
        out[(size_t)n * 16 + o] = vis * xi + (1.f - vis) * xp;
    }
}

extern "C" void kernel_launch(void* const* d_in, const int* in_sizes, int n_in,
                              void* d_out, int out_size, void* d_ws, size_t ws_size,
                              hipStream_t stream) {
    const float* fimg = (const float*)d_in[0];
    const float* fpts = (const float*)d_in[1];
    const int*   nbr  = (const int*)d_in[2];
    const float* Wimg = (const float*)d_in[3];
    const float* gi = (const float*)d_in[4];
    const float* bi = (const float*)d_in[5];
    const float* mi = (const float*)d_in[6];
    const float* vi = (const float*)d_in[7];
    const float* Wpts = (const float*)d_in[8];
    const float* gp = (const float*)d_in[9];
    const float* bp = (const float*)d_in[10];
    const float* mp = (const float*)d_in[11];
    const float* vp = (const float*)d_in[12];
    const float* Wvis = (const float*)d_in[13];
    const float* gv = (const float*)d_in[14];
    const float* bv = (const float*)d_in[15];
    const float* mv = (const float*)d_in[16];
    const float* vv = (const float*)d_in[17];
    const float* w2 = (const float*)d_in[18];
    float* out = (float*)d_out;
    float* ws = (float*)d_ws;

    // zero counters and accumulators (accA+accV contiguous)
    hipMemsetAsync(ws + CNT, 0, 2048 * sizeof(float), stream);
    hipMemsetAsync(ws + ACC, 0, (size_t)N_VOX * 48 * sizeof(float), stream);

    hipLaunchKernelGGL(build_pairs, dim3(4096), dim3(256), 0, stream, nbr, ws);
    hipLaunchKernelGGL(scatterA, dim3(125, 8), dim3(256), 0, stream,
                       fimg, fpts, Wimg, Wpts, ws);
    hipLaunchKernelGGL(finalizeA, dim3(1024), dim3(256), 0, stream,
                       fimg, fpts, Wimg, Wpts, ws, gi, bi, mi, vi, gp, bp, mp, vp);
    hipLaunchKernelGGL(scatterV, dim3(125, 8), dim3(256), 0, stream, Wvis, ws);
    hipLaunchKernelGGL(finalizeB, dim3(1024), dim3(256), 0, stream,
                       Wvis, ws, gv, bv, mv, vv, w2, out);
}